// Round 7
// baseline (1989.156 us; speedup 1.0000x reference)
//
#include <hip/hip_runtime.h>
#include <hip/hip_bf16.h>
#include <cstdio>

#define N_NODES 50000
#define E_EDGES 1000000
#define FIN 512
#define FOUT 128

__device__ __forceinline__ float bf2f(unsigned short u) {
    unsigned int x = ((unsigned int)u) << 16;
    return __builtin_bit_cast(float, x);
}
__device__ __forceinline__ unsigned short f2bf(float f) {
    unsigned int x = __builtin_bit_cast(unsigned int, f);
    unsigned int r = x + 0x7fffu + ((x >> 16) & 1u);  // RNE
    return (unsigned short)(r >> 16);
}

// managed dump buffer: [0..7] x raw dwords, [8..15] idx0 raw dwords,
// [16] f32flag, [17] i64flag, [24..31] d_out dwords after epilogue
__managed__ unsigned int g_dump[32];

// ---------------------------------------------------------------- dtype detection
__global__ void detect_kernel(const unsigned int* __restrict__ xraw,
                              const unsigned int* __restrict__ idxraw,
                              int* __restrict__ flags) {
    __shared__ int cnt, odd_nz;
    const int t = threadIdx.x;
    if (t == 0) { cnt = 0; odd_nz = 0; }
    __syncthreads();
    int local = 0;
    for (int i = t; i < 1024; i += 256) {
        unsigned int b = (xraw[i] >> 7) & 0xFF;   // bits 14..7 = low-half bf16 exponent field
        if (b >= 115 && b <= 133) local++;
    }
    atomicAdd(&cnt, local);
    if (t < 128) {
        if (idxraw[2 * t + 1] != 0u) atomicAdd(&odd_nz, 1);
    }
    __syncthreads();
    if (t == 0) {
        flags[0] = (cnt < 512) ? 1 : 0;   // 1 => floats are f32
        flags[1] = (odd_nz == 0) ? 1 : 0; // 1 => indices are int64
        g_dump[16] = (unsigned int)flags[0];
        g_dump[17] = (unsigned int)flags[1];
    }
    if (t < 8) {
        g_dump[t]     = xraw[t];
        g_dump[8 + t] = idxraw[t];
    }
}

// ---------------------------------------------------------------- zero acc
__global__ void zero_kernel(float4* __restrict__ p, int n4) {
    int i = blockIdx.x * blockDim.x + threadIdx.x;
    int stride = gridDim.x * blockDim.x;
    for (; i < n4; i += stride) p[i] = make_float4(0.f, 0.f, 0.f, 0.f);
}

// ---------------------------------------------------------------- GEMM (VALU, dtype-adaptive): pre = x @ W, f32 out
__global__ __launch_bounds__(256) void gemm_kernel(const void* __restrict__ xv,
                                                   const void* __restrict__ Wv,
                                                   float* __restrict__ pre,
                                                   const int* __restrict__ flags) {
    __shared__ float sx[8 * FIN];   // 16 KB: 8 staged x-rows as f32

    const int tid = threadIdx.x;
    const int r0  = blockIdx.x * 8;  // 50000 = 8 * 6250 exactly
    const int f32m = flags[0];

    if (f32m) {
        const float4* xp = (const float4*)((const float*)xv + (size_t)r0 * FIN);
#pragma unroll
        for (int j = 0; j < 4; j++)
            ((float4*)sx)[tid * 4 + j] = xp[tid * 4 + j];
    } else {
        const ushort* xh = (const ushort*)xv + (size_t)r0 * FIN;
        const int base = tid * 16;
        ushort tmp[16];
        *(uint4*)(tmp)     = *(const uint4*)(xh + base);
        *(uint4*)(tmp + 8) = *(const uint4*)(xh + base + 8);
#pragma unroll
        for (int i = 0; i < 16; i++) sx[base + i] = bf2f(tmp[i]);
    }
    __syncthreads();

    const int col = tid & 127;
    const int g   = tid >> 7;        // 0 or 1
    float acc[4] = {0.f, 0.f, 0.f, 0.f};

    if (f32m) {
        const float* Wf = (const float*)Wv;
#pragma unroll 4
        for (int k = 0; k < FIN; k++) {
            float w = Wf[(size_t)k * FOUT + col];
#pragma unroll
            for (int j = 0; j < 4; j++)
                acc[j] = fmaf(sx[(4 * g + j) * FIN + k], w, acc[j]);
        }
    } else {
        const ushort* Wh = (const ushort*)Wv;
#pragma unroll 4
        for (int k = 0; k < FIN; k++) {
            float w = bf2f(Wh[(size_t)k * FOUT + col]);
#pragma unroll
            for (int j = 0; j < 4; j++)
                acc[j] = fmaf(sx[(4 * g + j) * FIN + k], w, acc[j]);
        }
    }

#pragma unroll
    for (int j = 0; j < 4; j++) {
        int row = r0 + 4 * g + j;
        pre[(size_t)row * FOUT + col] = acc[j];
    }
}

// ---------------------------------------------------------------- scatter (both supports), one wave per edge
__global__ __launch_bounds__(256) void scatter_kernel(
        const float* __restrict__ pre,
        const void* __restrict__ idx0v, const void* __restrict__ vals0v,
        const void* __restrict__ idx1v, const void* __restrict__ vals1v,
        float* __restrict__ acc, const int* __restrict__ flags) {
    const int gw   = (int)((blockIdx.x * blockDim.x + threadIdx.x) >> 6);
    const int lane = threadIdx.x & 63;
    const int nw   = (int)((gridDim.x * blockDim.x) >> 6);
    const int total = 2 * E_EDGES;
    const int f32m = flags[0];
    const int i64m = flags[1];

    for (int e = gw; e < total; e += nw) {
        const void* idxv;
        const void* valsv;
        float* dst;
        int ee;
        if (e < E_EDGES) { idxv = idx0v; valsv = vals0v; dst = acc; ee = e; }
        else             { idxv = idx1v; valsv = vals1v; dst = acc + (size_t)N_NODES * FOUT; ee = e - E_EDGES; }

        int row, col;
        if (i64m) {
            const int* idx32 = (const int*)idxv;   // int64 pairs (value, 0)
            row = idx32[2 * (size_t)ee];
            col = idx32[2 * ((size_t)E_EDGES + ee)];
        } else {
            const int* idx32 = (const int*)idxv;
            row = idx32[ee];
            col = idx32[E_EDGES + ee];
        }
        float v = f32m ? ((const float*)valsv)[ee] : bf2f(((const ushort*)valsv)[ee]);

        float2 p = *(const float2*)(pre + (size_t)col * FOUT + lane * 2);
        float* d = dst + (size_t)row * FOUT + lane * 2;
        atomicAdd(d,     v * p.x);
        atomicAdd(d + 1, v * p.y);
    }
}

// ---------------------------------------------------------------- epilogue: out = relu(acc + bias), dtype-adaptive
__global__ void epilogue_kernel(const float4* __restrict__ acc,
                                const void* __restrict__ biasv,
                                void* __restrict__ outv,
                                const int* __restrict__ flags) {
    const int total4 = 2 * N_NODES * FOUT / 4;
    const int f32m = flags[0];
    int i = blockIdx.x * blockDim.x + threadIdx.x;
    int stride = gridDim.x * blockDim.x;
    for (; i < total4; i += stride) {
        float4 a = acc[i];
        int cb = (i * 4) & (FOUT - 1);
        float b0, b1, b2, b3;
        if (f32m) {
            const float* bf = (const float*)biasv;
            b0 = bf[cb]; b1 = bf[cb + 1]; b2 = bf[cb + 2]; b3 = bf[cb + 3];
        } else {
            const ushort* bh = (const ushort*)biasv;
            b0 = bf2f(bh[cb]); b1 = bf2f(bh[cb + 1]); b2 = bf2f(bh[cb + 2]); b3 = bf2f(bh[cb + 3]);
        }
        float r0 = fmaxf(a.x + b0, 0.f);
        float r1 = fmaxf(a.y + b1, 0.f);
        float r2 = fmaxf(a.z + b2, 0.f);
        float r3 = fmaxf(a.w + b3, 0.f);
        if (f32m) {
            ((float4*)outv)[i] = make_float4(r0, r1, r2, r3);
        } else {
            ushort4 o;
            o.x = f2bf(r0); o.y = f2bf(r1); o.z = f2bf(r2); o.w = f2bf(r3);
            ((ushort4*)outv)[i] = o;
        }
    }
}

// ---------------------------------------------------------------- dump first 8 dwords of out
__global__ void dump_out_kernel(const unsigned int* __restrict__ out) {
    int t = threadIdx.x;
    if (t < 8) g_dump[24 + t] = out[t];
}

static void host_cb(void* ud) {
    (void)ud;
    fprintf(stderr, "[probe] flags: f32=%u i64=%u\n", g_dump[16], g_dump[17]);
    fprintf(stderr, "[probe] x[0..7]:   %08x %08x %08x %08x %08x %08x %08x %08x\n",
            g_dump[0], g_dump[1], g_dump[2], g_dump[3], g_dump[4], g_dump[5], g_dump[6], g_dump[7]);
    fprintf(stderr, "[probe] idx[0..7]: %08x %08x %08x %08x %08x %08x %08x %08x\n",
            g_dump[8], g_dump[9], g_dump[10], g_dump[11], g_dump[12], g_dump[13], g_dump[14], g_dump[15]);
    fprintf(stderr, "[probe] out[0..7]: %08x %08x %08x %08x %08x %08x %08x %08x\n",
            g_dump[24], g_dump[25], g_dump[26], g_dump[27], g_dump[28], g_dump[29], g_dump[30], g_dump[31]);
    fflush(stderr);
}

extern "C" void kernel_launch(void* const* d_in, const int* in_sizes, int n_in,
                              void* d_out, int out_size, void* d_ws, size_t ws_size,
                              hipStream_t stream) {
    (void)in_sizes; (void)n_in; (void)out_size; (void)ws_size;
    const void* x     = d_in[0];   // [N, FIN] f32 or bf16
    const void* idx0  = d_in[1];   // [2, E] int64 or int32
    const void* vals0 = d_in[2];   // [E]
    const void* idx1  = d_in[3];   // [2, E]
    const void* vals1 = d_in[4];   // [E]
    const void* W     = d_in[5];   // [FIN, FOUT]
    const void* bias  = d_in[6];   // [FOUT]

    // ws layout: pre f32 [N*FOUT] at 0 (25.6MB), acc f32 [2*N*FOUT] at 32MB (51.2MB),
    // flags int[2] at 400MB
    float* pre   = (float*)d_ws;
    float* acc   = (float*)((char*)d_ws + (size_t)32 * 1024 * 1024);
    int*   flags = (int*)((char*)d_ws + (size_t)400 * 1024 * 1024);

    const int out_n = 2 * N_NODES * FOUT;
    const int acc4  = out_n / 4;

    detect_kernel<<<dim3(1), dim3(256), 0, stream>>>(
        (const unsigned int*)x, (const unsigned int*)idx0, flags);
    zero_kernel<<<dim3(3200), dim3(256), 0, stream>>>((float4*)acc, acc4);
    gemm_kernel<<<dim3(N_NODES / 8), dim3(256), 0, stream>>>(x, W, pre, flags);
    scatter_kernel<<<dim3(2048), dim3(256), 0, stream>>>(pre, idx0, vals0, idx1, vals1, acc, flags);
    epilogue_kernel<<<dim3(3200), dim3(256), 0, stream>>>((const float4*)acc, bias, d_out, flags);
    dump_out_kernel<<<dim3(1), dim3(64), 0, stream>>>((const unsigned int*)d_out);
    hipLaunchHostFunc(stream, host_cb, nullptr);
}